// Round 3
// baseline (139.129 us; speedup 1.0000x reference)
//
#include <hip/hip_runtime.h>
#include <hip/hip_fp16.h>
#include <cmath>

#define NLOD 10

// ---------------------------------------------------------------------------
// LDS layout (all compile-time):
//   [hashed levels 4..9]  4825 entries   bytes      0 .. 38600
//   [dense grids 0..3]    4930 vertices  bytes  38600 .. 78040
// Hashed levels come FIRST so every ds_read offset immediate (level base +
// corner delta) stays < 65536.  78040 B/block -> two 1024-thread blocks/CU
// (156 KB of 160 KB), full 2048-thread occupancy retained.
//
// Levels 0..3 are staged DE-HASHED (hash+mod once per vertex per block at
// staging; hot loop addresses by linear vertex coordinate).
//
// This round: every level is split into explicit phases per 2-point pair --
//   [addr+weights A,B] -> [issue 16 ds_read_b64 into raw arrays] -> [48 fma]
// so gather latency of level L hides under the fma block of level L-1 and
// the address math of level L+1.  All array indices are static after unroll
// (rule #20), so raw[] lives in VGPRs.
// ---------------------------------------------------------------------------
static constexpr int HSIZES[6] = {324, 529, 900, 1024, 1024, 1024}; // levels 4..9
static constexpr int HENT[6]   = {0, 324, 853, 1753, 2777, 3801};   // entry offsets
static constexpr int TOTAL_ENTRIES = 9755;                           // 4825 + 4930
// LDS bytes = 9755 * 8 = 78040

struct ResArr { int r[NLOD]; };

// Three v_fma_mix_f32 consume the f16 halves in place via op_sel
// (numerically identical to fpext+fma, both exact/fused).
__device__ __forceinline__ void fmix_accum(uint2 raw, float wt,
                                           float& a0, float& a1, float& a2)
{
    asm("v_fma_mix_f32 %0, %1, %2, %0 op_sel_hi:[1,0,0]"
        : "+v"(a0) : "v"(raw.x), "v"(wt));
    asm("v_fma_mix_f32 %0, %1, %2, %0 op_sel:[1,0,0] op_sel_hi:[1,0,0]"
        : "+v"(a1) : "v"(raw.x), "v"(wt));
    asm("v_fma_mix_f32 %0, %1, %2, %0 op_sel_hi:[1,0,0]"
        : "+v"(a2) : "v"(raw.y), "v"(wt));
}

// Shared weight computation.  Corner order matches reference OFFSETS:
// c = 4i+2j+k, (i,j,k) lexicographic.
__device__ __forceinline__ void make_weights(float wx, float wy, float wz,
                                             float (&wt)[8])
{
    float wx0 = 1.0f - wx, wy0 = 1.0f - wy, wz0 = 1.0f - wz;
    float w00 = wx0 * wy0, w01 = wx0 * wy, w10 = wx * wy0, w11 = wx * wy;
    wt[0] = w00 * wz0; wt[1] = w00 * wz;
    wt[2] = w01 * wz0; wt[3] = w01 * wz;
    wt[4] = w10 * wz0; wt[5] = w10 * wz;
    wt[6] = w11 * wz0; wt[7] = w11 * wz;
}

// ---------------------------------------------------------------------------
// Hashed levels 4..9: address phase.  ofs[c] = byte offset into this level's
// table.  Pow2 folds the *8 byte scale into the hash components
// ((h<<3) mod (8*SIZE) == 8*(h mod SIZE) iff SIZE pow2); non-pow2 uses the
// constexpr-divisor magic-mod.
// ---------------------------------------------------------------------------
template <int SIZE>
__device__ __forceinline__ void hash_setup(int res, float px, float py, float pz,
                                           unsigned (&ofs)[8], float (&wt)[8])
{
    constexpr bool POW2 = (SIZE & (SIZE - 1)) == 0;
    constexpr unsigned P1 = 2654435761u, P2 = 805459861u;

    const float s = (float)(res - 1);
    float fx = px * s, fy = py * s, fz = pz * s;

    // clip(floor(x),0,res-2) == floor(x) here, exactly (px in [0,1),
    // res-1 in [6,64]; the product never rounds up to res-1).
    float gx = floorf(fx), gy = floorf(fy), gz = floorf(fz);
    float wx = fx - gx, wy = fy - gy, wz = fz - gz;

    unsigned ux = (unsigned)(int)gx;
    unsigned uy = (unsigned)(int)gy;
    unsigned uz = (unsigned)(int)gz;

    unsigned hx0, hx1, hy0, hy1, hz0, hz1;
    if constexpr (POW2) {
        hx0 = ux << 3;        hx1 = hx0 + 8u;
        hy0 = uy * (P1 * 8u); hy1 = hy0 + (P1 * 8u);
        hz0 = uz * (P2 * 8u); hz1 = hz0 + (P2 * 8u);
    } else {
        hx0 = ux;       hx1 = ux + 1u;
        hy0 = uy * P1;  hy1 = hy0 + P1;
        hz0 = uz * P2;  hz1 = hz0 + P2;
    }
    unsigned h00 = hx0 ^ hy0, h01 = hx0 ^ hy1;
    unsigned h10 = hx1 ^ hy0, h11 = hx1 ^ hy1;

    unsigned h[8] = { h00 ^ hz0, h00 ^ hz1, h01 ^ hz0, h01 ^ hz1,
                      h10 ^ hz0, h10 ^ hz1, h11 ^ hz0, h11 ^ hz1 };
#pragma unroll
    for (int c = 0; c < 8; ++c) {
        if constexpr (POW2) ofs[c] = h[c] & (unsigned)((SIZE - 1) * 8);
        else                ofs[c] = (h[c] % (unsigned)SIZE) * 8u;
    }
    make_weights(wx, wy, wz, wt);
}

// Hashed level, two points: addr A, addr B, 16 loads, 24+24 fma.
template <int SIZE>
__device__ __forceinline__ void hash2(const char* __restrict__ cb, int res,
    float ax, float ay, float az, float& A0, float& A1, float& A2,
    float bx, float by, float bz, float& B0, float& B1, float& B2)
{
    unsigned oa[8], ob[8];
    float    wa[8], wb[8];
    hash_setup<SIZE>(res, ax, ay, az, oa, wa);
    hash_setup<SIZE>(res, bx, by, bz, ob, wb);

    uint2 ra[8], rb[8];
#pragma unroll
    for (int c = 0; c < 8; ++c)
        ra[c] = *reinterpret_cast<const uint2*>(cb + oa[c]);
#pragma unroll
    for (int c = 0; c < 8; ++c)
        rb[c] = *reinterpret_cast<const uint2*>(cb + ob[c]);

#pragma unroll
    for (int c = 0; c < 8; ++c) fmix_accum(ra[c], wa[c], A0, A1, A2);
#pragma unroll
    for (int c = 0; c < 8; ++c) fmix_accum(rb[c], wb[c], B0, B1, B2);
}

// ---------------------------------------------------------------------------
// Dense (de-hashed) levels 0..3.  base = ((gx*RES+gy)*RES+gz)*8 computed
// exactly in float (2 fma + cvt); corner deltas are compile-time constants
// folded into the ds_read offset immediates.
// ---------------------------------------------------------------------------
template <int RES>
__device__ __forceinline__ void dense_setup(float px, float py, float pz,
                                            unsigned& base, float (&wt)[8])
{
    constexpr float S = (float)(RES - 1);
    float fx = px * S, fy = py * S, fz = pz * S;
    float gx = floorf(fx), gy = floorf(fy), gz = floorf(fz);
    float wx = fx - gx, wy = fy - gy, wz = fz - gz;

    float lin = fmaf(gx, (float)(RES * RES * 8),
                 fmaf(gy, (float)(RES * 8), gz * 8.0f));
    base = (unsigned)lin;   // exact: lin is a non-negative integer < 2^24
    make_weights(wx, wy, wz, wt);
}

template <int RES, int LBASE>
__device__ __forceinline__ void dense2(const char* __restrict__ lds,
    float ax, float ay, float az, float& A0, float& A1, float& A2,
    float bx, float by, float bz, float& B0, float& B1, float& B2)
{
    unsigned baA, baB;
    float wa[8], wb[8];
    dense_setup<RES>(ax, ay, az, baA, wa);
    dense_setup<RES>(bx, by, bz, baB, wb);

    uint2 ra[8], rb[8];
#pragma unroll
    for (int c = 0; c < 8; ++c) {
        const int d = LBASE + (((c >> 2) * RES * RES + ((c >> 1) & 1) * RES + (c & 1)) * 8);
        ra[c] = *reinterpret_cast<const uint2*>(lds + baA + d);
    }
#pragma unroll
    for (int c = 0; c < 8; ++c) {
        const int d = LBASE + (((c >> 2) * RES * RES + ((c >> 1) & 1) * RES + (c & 1)) * 8);
        rb[c] = *reinterpret_cast<const uint2*>(lds + baB + d);
    }

#pragma unroll
    for (int c = 0; c < 8; ++c) fmix_accum(ra[c], wa[c], A0, A1, A2);
#pragma unroll
    for (int c = 0; c < 8; ++c) fmix_accum(rb[c], wb[c], B0, B1, B2);
}

// Stage one dense de-hashed grid: per vertex (x,y,z), compute the Instant-NGP
// hash once, gather the codebook entry, compress to f16, store at the linear
// vertex index.  ~5 vertices/thread for 1024-thread blocks.
template <int RES, int SIZE, int ENT>
__device__ __forceinline__ void stage_dense(const float* __restrict__ src,
                                            __half* cbh)
{
    constexpr unsigned P1 = 2654435761u, P2 = 805459861u;
    for (int v = threadIdx.x; v < RES * RES * RES; v += 1024) {
        int z = v % RES;
        int t = v / RES;
        int y = t % RES;
        int x = t / RES;
        unsigned h = (unsigned)x ^ ((unsigned)y * P1) ^ ((unsigned)z * P2);
        unsigned idx = h % (unsigned)SIZE;        // constexpr divisor
        const float* s = src + idx * 3;
        __half2* d = reinterpret_cast<__half2*>(cbh + (ENT + v) * 4);
        d[0] = __floats2half2_rn(s[0], s[1]);
        d[1] = __floats2half2_rn(s[2], 0.0f);
    }
}

__global__ __launch_bounds__(1024, 8)
void hashgrid_kernel(const float* __restrict__ pts,
                     const float* __restrict__ c0, const float* __restrict__ c1,
                     const float* __restrict__ c2, const float* __restrict__ c3,
                     const float* __restrict__ c4, const float* __restrict__ c5,
                     const float* __restrict__ c6, const float* __restrict__ c7,
                     const float* __restrict__ c8, const float* __restrict__ c9,
                     float* __restrict__ out, int npts, ResArr res)
{
    __shared__ __half cbh[TOTAL_ENTRIES * 4];   // 78040 B
    const char* lds = reinterpret_cast<const char*>(cbh);

    // ---- stage hashed levels 4..9 (copy + compress) ----
    {
        const float* hs[6] = {c4, c5, c6, c7, c8, c9};
#pragma unroll
        for (int L = 0; L < 6; ++L) {
            for (int e = threadIdx.x; e < HSIZES[L]; e += 1024) {
                const float* s = hs[L] + e * 3;
                __half2* d = reinterpret_cast<__half2*>(cbh + (HENT[L] + e) * 4);
                d[0] = __floats2half2_rn(s[0], s[1]);
                d[1] = __floats2half2_rn(s[2], 0.0f);
            }
        }
    }
    // ---- stage dense de-hashed grids, levels 0..3 ----
    stage_dense< 7,  49, 4825>(c0, cbh);
    stage_dense< 8,  64, 5168>(c1, cbh);
    stage_dense<11, 121, 5680>(c2, cbh);
    stage_dense<14, 196, 7011>(c3, cbh);
    __syncthreads();

    // 512 blocks x 1024 thr (exactly 2 blocks/CU, no block imbalance),
    // 2 points/thread/iter, 2 iterations for npts = 2M.
    const int S = gridDim.x * blockDim.x;
    for (int n = blockIdx.x * blockDim.x + threadIdx.x; n < npts; n += 2 * S) {
        const int m = n + S;
        const bool hasB = (m < npts);
        const int mc = hasB ? m : n;      // clamp: B duplicates A, store suppressed

        float ax = pts[n * 3 + 0], ay = pts[n * 3 + 1], az = pts[n * 3 + 2];
        float bx = pts[mc * 3 + 0], by = pts[mc * 3 + 1], bz = pts[mc * 3 + 2];

        float A0 = 0.0f, A1 = 0.0f, A2 = 0.0f;
        float B0 = 0.0f, B1 = 0.0f, B2 = 0.0f;

        // levels 0..3: dense de-hashed grids
#define DLEVEL(RES, ENT)                                    \
        dense2<RES, (ENT) * 8>(lds, ax, ay, az, A0, A1, A2, \
                                    bx, by, bz, B0, B1, B2);
        DLEVEL( 7, 4825)
        DLEVEL( 8, 5168)
        DLEVEL(11, 5680)
        DLEVEL(14, 7011)
#undef DLEVEL

        // levels 4..9: hashed lookups (magic-mod for 324/529/900, masked
        // pow2 for the 1024s)
#define HLEVEL(SZ, HL)                                                 \
        hash2<SZ>(lds + HENT[HL] * 8, res.r[(HL) + 4],                 \
                  ax, ay, az, A0, A1, A2, bx, by, bz, B0, B1, B2);
        HLEVEL( 324, 0)
        HLEVEL( 529, 1)
        HLEVEL( 900, 2)
        HLEVEL(1024, 3)
        HLEVEL(1024, 4)
        HLEVEL(1024, 5)
#undef HLEVEL

        out[n * 3 + 0] = A0;
        out[n * 3 + 1] = A1;
        out[n * 3 + 2] = A2;
        if (hasB) {
            out[m * 3 + 0] = B0;
            out[m * 3 + 1] = B1;
            out[m * 3 + 2] = B2;
        }
    }
}

extern "C" void kernel_launch(void* const* d_in, const int* in_sizes, int n_in,
                              void* d_out, int out_size, void* d_ws, size_t ws_size,
                              hipStream_t stream)
{
    const float* pts = (const float*)d_in[0];
    const int npts = in_sizes[0] / 3;

    // Replicate numpy's exact double-precision LOD computation (glibc libm):
    // LOD 9 sits at 6*b^9 == 64.0 +/- ~1e-14, floor() is boundary-sensitive.
    // (Only levels 4..9 are consumed at runtime; 0..3 are compile-time dense.)
    ResArr ra;
    const double b = exp((log(64.0) - log(6.0)) / 9.0);
    for (int l = 0; l < NLOD; ++l)
        ra.r[l] = (int)(1.0 + floor(6.0 * pow(b, (double)l)));

    // 512 blocks x 1024 thr: 2 blocks/CU (156 KB LDS), 32 waves/CU.
    hashgrid_kernel<<<dim3(512), dim3(1024), 0, stream>>>(
        pts,
        (const float*)d_in[1], (const float*)d_in[2], (const float*)d_in[3],
        (const float*)d_in[4], (const float*)d_in[5], (const float*)d_in[6],
        (const float*)d_in[7], (const float*)d_in[8], (const float*)d_in[9],
        (const float*)d_in[10],
        (float*)d_out, npts, ra);
}